// Round 4
// baseline (196.573 us; speedup 1.0000x reference)
//
#include <hip/hip_runtime.h>
#include <hip/hip_bf16.h>

#define Tsz 2048
#define Csz 1024
#define Hn 16

typedef short s8v __attribute__((ext_vector_type(8)));
typedef short s4v __attribute__((ext_vector_type(4)));
typedef float f4v __attribute__((ext_vector_type(4)));

#define QSCALE (0.125f * 1.44269504088896f)  // 1/sqrt(64) * log2(e), folded into Q

// fast bf16 round (bits+0x8000)>>16 : 2 VALU vs ~6 for software RNE
__device__ __forceinline__ unsigned short bfr(float x) {
    return (unsigned short)((__builtin_bit_cast(unsigned, x) + 0x8000u) >> 16);
}
__device__ __forceinline__ unsigned pack2_rn(float a, float b) {
    const unsigned ua = __builtin_bit_cast(unsigned, a) + 0x8000u;
    const unsigned ub = __builtin_bit_cast(unsigned, b) + 0x8000u;
    return (ua >> 16) | (ub & 0xFFFF0000u);
}

__device__ __forceinline__ void gload_lds(const void* g, void* l) {
    __builtin_amdgcn_global_load_lds(
        (const __attribute__((address_space(1))) void*)g,
        (__attribute__((address_space(3))) void*)l, 16, 0, 0);
}

// ---------------- fp32 -> bf16 conversion, exact-size grid (8192 blocks) ----------------
__global__ void cvt6(const float* __restrict__ x, const float* __restrict__ wq,
                     const float* __restrict__ wk, const float* __restrict__ wv,
                     const float* __restrict__ wp,
                     short* __restrict__ xo, short* __restrict__ qo,
                     short* __restrict__ ko, short* __restrict__ vo,
                     short* __restrict__ po) {
    const int bx = blockIdx.x;
    const float* in; short* out; int ib;
    if (bx < 4096) { in = x; out = xo; ib = bx; }
    else {
        const int r = bx - 4096, w = r >> 10;
        ib = r & 1023;
        switch (w) {
            case 0: in = wq; out = qo; break;
            case 1: in = wk; out = ko; break;
            case 2: in = wv; out = vo; break;
            default: in = wp; out = po; break;
        }
    }
    const int i = ib * 1024 + threadIdx.x * 4;
    float4 v = *(const float4*)(in + i);
    int2 o;
    o.x = (int)pack2_rn(v.x, v.y);
    o.y = (int)pack2_rn(v.z, v.w);
    *(int2*)(out + i) = o;
}

// ---------------- fused QKV GEMM (m97 structure) ----------------
__global__ __launch_bounds__(256, 3) void qkv_gemm(
    const short* __restrict__ X,
    const short* __restrict__ Wq, const short* __restrict__ Wk, const short* __restrict__ Wv,
    const float* __restrict__ bq, const float* __restrict__ bk, const float* __restrict__ bv,
    short* __restrict__ Qo, short* __restrict__ Ko, short* __restrict__ Vto)
{
    const int z = blockIdx.z;
    const short* W = (z == 0) ? Wq : (z == 1) ? Wk : Wv;
    const float* bias = (z == 0) ? bq : (z == 1) ? bk : bv;

    __shared__ __align__(16) short Ash[128 * 32];
    __shared__ __align__(16) short Bsh[128 * 32];
    __shared__ __align__(16) short TR[64 * 72];   // transpose staging (z==2 epilogue)

    const int tid = threadIdx.x, lane = tid & 63, wave = tid >> 6;
    const int ln = lane & 15, hi = lane >> 4;
    const int m0 = blockIdx.x * 128, n0 = blockIdx.y * 128;
    const int wm = (wave >> 1) * 64, wn = (wave & 1) * 64;

    const short* Ag = X + (size_t)(m0 + (tid >> 2)) * Csz + (tid & 3) * 8;
    const short* Bg = W + (size_t)(n0 + (tid >> 2)) * Csz + (tid & 3) * 8;

    f4v acc[4][4];
    #pragma unroll
    for (int mt = 0; mt < 4; mt++)
        #pragma unroll
        for (int nt = 0; nt < 4; nt++)
            #pragma unroll
            for (int i = 0; i < 4; i++) acc[mt][nt][i] = 0.f;

    for (int k0 = 0; k0 < Csz; k0 += 32) {
        __syncthreads();
        gload_lds(Ag + k0, Ash + tid * 8);
        gload_lds(Ag + k0 + (size_t)64 * Csz, Ash + 2048 + tid * 8);
        gload_lds(Bg + k0, Bsh + tid * 8);
        gload_lds(Bg + k0 + (size_t)64 * Csz, Bsh + 2048 + tid * 8);
        __syncthreads();

        s8v af[4], bfr_[4];
        #pragma unroll
        for (int mt = 0; mt < 4; mt++)
            af[mt] = *(const s8v*)(Ash + (wm + mt * 16 + ln) * 32 + hi * 8);
        #pragma unroll
        for (int nt = 0; nt < 4; nt++)
            bfr_[nt] = *(const s8v*)(Bsh + (wn + nt * 16 + ln) * 32 + hi * 8);
        #pragma unroll
        for (int mt = 0; mt < 4; mt++)
            #pragma unroll
            for (int nt = 0; nt < 4; nt++)
                acc[mt][nt] = __builtin_amdgcn_mfma_f32_16x16x32_bf16(af[mt], bfr_[nt], acc[mt][nt], 0, 0, 0);
    }

    if (z == 2) {
        const int b = m0 >> 11, t0 = m0 & 2047;
        float bvv[4];
        #pragma unroll
        for (int nt = 0; nt < 4; nt++) bvv[nt] = bias[n0 + wn + nt * 16 + ln];
        #pragma unroll
        for (int ph = 0; ph < 4; ph++) {
            const int mh = ph >> 1, nh = ph & 1;
            __syncthreads();
            if ((wave >> 1) == mh && (wave & 1) == nh) {
                #pragma unroll
                for (int mt = 0; mt < 4; mt++)
                    #pragma unroll
                    for (int nt = 0; nt < 4; nt++) {
                        int2 pk;
                        pk.x = (int)pack2_rn(acc[mt][nt][0] + bvv[nt], acc[mt][nt][1] + bvv[nt]);
                        pk.y = (int)pack2_rn(acc[mt][nt][2] + bvv[nt], acc[mt][nt][3] + bvv[nt]);
                        *(int2*)(TR + (nt * 16 + ln) * 72 + mt * 16 + hi * 4) = pk;
                    }
            }
            __syncthreads();
            const int chl = tid >> 2, seg = tid & 3;
            const s8v r0 = *(const s8v*)(TR + chl * 72 + seg * 16);
            const s8v r1 = *(const s8v*)(TR + chl * 72 + seg * 16 + 8);
            short* dst = Vto + (size_t)(b * 1024 + n0 + nh * 64 + chl) * Tsz + t0 + mh * 64 + seg * 16;
            *(s8v*)(dst) = r0;
            *(s8v*)(dst + 8) = r1;
        }
        return;
    }

    const float scale = (z == 0) ? QSCALE : 1.0f;
    short* out = (z == 0) ? Qo : Ko;

    #pragma unroll
    for (int nt = 0; nt < 4; nt++) {
        const int col = n0 + wn + nt * 16 + ln;
        const float bvv = bias[col];
        #pragma unroll
        for (int mt = 0; mt < 4; mt++) {
            const int row0 = m0 + wm + mt * 16 + hi * 4;
            #pragma unroll
            for (int i = 0; i < 4; i++)
                out[(size_t)(row0 + i) * Csz + col] = (short)bfr((acc[mt][nt][i] + bvv) * scale);
        }
    }
}

// ---------------- output projection GEMM (f32 out), 128x64 tiles, grid (32,16) ----------------
__global__ __launch_bounds__(256, 2) void proj_gemm(
    const short* __restrict__ A, const short* __restrict__ W,
    const float* __restrict__ bias, float* __restrict__ out)
{
    __shared__ __align__(16) short Ash[128 * 32];
    __shared__ __align__(16) short Bsh[64 * 32];

    const int tid = threadIdx.x, lane = tid & 63, wave = tid >> 6;
    const int ln = lane & 15, hi = lane >> 4;
    const int m0 = blockIdx.x * 128, n0 = blockIdx.y * 64;
    const int wm = (wave >> 1) * 64, wn = (wave & 1) * 32;

    const short* Ag = A + (size_t)(m0 + (tid >> 2)) * Csz + (tid & 3) * 8;
    const short* Bg = W + (size_t)(n0 + (tid >> 2)) * Csz + (tid & 3) * 8;

    f4v acc[4][2];
    #pragma unroll
    for (int mt = 0; mt < 4; mt++)
        #pragma unroll
        for (int nt = 0; nt < 2; nt++)
            #pragma unroll
            for (int i = 0; i < 4; i++) acc[mt][nt][i] = 0.f;

    for (int k0 = 0; k0 < Csz; k0 += 32) {
        __syncthreads();
        gload_lds(Ag + k0, Ash + tid * 8);
        gload_lds(Ag + k0 + (size_t)64 * Csz, Ash + 2048 + tid * 8);
        gload_lds(Bg + k0, Bsh + tid * 8);
        __syncthreads();

        s8v af[4], bfr_[2];
        #pragma unroll
        for (int mt = 0; mt < 4; mt++)
            af[mt] = *(const s8v*)(Ash + (wm + mt * 16 + ln) * 32 + hi * 8);
        #pragma unroll
        for (int nt = 0; nt < 2; nt++)
            bfr_[nt] = *(const s8v*)(Bsh + (wn + nt * 16 + ln) * 32 + hi * 8);
        #pragma unroll
        for (int mt = 0; mt < 4; mt++)
            #pragma unroll
            for (int nt = 0; nt < 2; nt++)
                acc[mt][nt] = __builtin_amdgcn_mfma_f32_16x16x32_bf16(af[mt], bfr_[nt], acc[mt][nt], 0, 0, 0);
    }

    #pragma unroll
    for (int nt = 0; nt < 2; nt++) {
        const int col = n0 + wn + nt * 16 + ln;
        const float bvv = bias[col];
        #pragma unroll
        for (int mt = 0; mt < 4; mt++)
            #pragma unroll
            for (int i = 0; i < 4; i++)
                out[(size_t)(m0 + wm + mt * 16 + hi * 4 + i) * Csz + col] = acc[mt][nt][i] + bvv;
    }
}

// ---------------- Flash attention v13: v10 mapping + XOR-swizzled K/V + pipelined PV ----------------
// Base: v10 (verified green). Changes:
//  (1) K/V LDS pitch 72->64 shorts (128B) with 16B-slot XOR swizzle slot^=(row&7);
//      applied identically to the reg->LDS staging write and the fragment reads.
//      Eliminates the 8-lanes-per-bank-group pattern on ds_read_b128.
//  (2) PV pipelined one key-tile behind: P(kb) is written to Psh[kb&1]; PV(kb-1)
//      reads Psh[(kb-1)&1] (latency long expired) with V-fragments held in regs
//      from the previous iteration. Removes the ds_write->lgkmcnt->ds_read chain
//      from the per-tile critical path. Epilogue drains the last tile.
// P path layout/code is byte-identical to v10 (pitch 72), just double-buffered.
__global__ __launch_bounds__(256, 4) void attn13(
    const short* __restrict__ Q, const short* __restrict__ Kg,
    const short* __restrict__ Vt, short* __restrict__ Y)
{
    __shared__ __align__(16) short Ksh[64 * 64];         // [key][slot-swizzled d], pitch 64
    __shared__ __align__(16) short Vsh[64 * 64];         // [d][slot-swizzled key], pitch 64
    __shared__ __align__(16) short Psh[2][4][16 * 72];   // [buf][wave][q][key], pitch 72

    const int tid = threadIdx.x, lane = tid & 63, wave = tid >> 6;
    const int ln = lane & 15, hi = lane >> 4;

    // block -> (q-tile, head): v10 mapping (verified)
    const int n = blockIdx.x;
    const int c = n & 255, j = n >> 8;
    const int bh = (j << 3) | (c >> 5);               // 0..31
    const int t = c & 31;
    const int qt = (j & 1) ? t : 31 - t;              // q-tile index 0..31

    const size_t base = (size_t)(bh >> 4) * Tsz * Csz + (size_t)(bh & 15) * 64;
    const size_t vtbase = (size_t)bh * 64 * Tsz;
    const int qrel = wave * 16 + ln;                  // within-tile q row (MFMA n-col)

    s8v qf[2];
    #pragma unroll
    for (int kk = 0; kk < 2; kk++)
        qf[kk] = *(const s8v*)(Q + base + (size_t)(qt * 64 + qrel) * Csz + kk * 32 + hi * 8);

    f4v o[4];
    float lsum = 0.f;
    #pragma unroll
    for (int dt = 0; dt < 4; dt++)
        #pragma unroll
        for (int i = 0; i < 4; i++) o[dt][i] = 0.f;

    // staging: 256 threads, each 2x16B of K and 2x16B of V per tile.
    // thread -> (row sr / sr+32, 16B-slot scs); LDS slot XOR-swizzled by row&7
    // ((sr+32)&7 == sr&7, so one swizzled offset serves both rows).
    const int sr = tid >> 3, scs = tid & 7;
    const short* Kp = Kg + base + (size_t)sr * Csz + scs * 8;
    const short* Vp = Vt + vtbase + (size_t)sr * Tsz + scs * 8;
    const int swo = sr * 64 + (scs ^ (sr & 7)) * 8;
    const int nkb = qt + 1;                           // exactly the causal tiles

    // fragment-read offsets (row = nt*16+ln, slot = kk*4+hi, swizzle by ln&7)
    int foff[2][4];
    #pragma unroll
    for (int nt = 0; nt < 4; nt++)
        #pragma unroll
        for (int kk = 0; kk < 2; kk++)
            foff[kk][nt] = (nt * 16 + ln) * 64 + (((kk * 4 + hi) ^ (ln & 7)) * 8);

    // prologue: tile 0 -> LDS
    s8v k0 = *(const s8v*)(Kp);
    s8v k1 = *(const s8v*)(Kp + (size_t)32 * Csz);
    s8v v0 = *(const s8v*)(Vp);
    s8v v1 = *(const s8v*)(Vp + (size_t)32 * Tsz);
    *(s8v*)(&Ksh[swo]) = k0;
    *(s8v*)(&Ksh[swo + 32 * 64]) = k1;
    *(s8v*)(&Vsh[swo]) = v0;
    *(s8v*)(&Vsh[swo + 32 * 64]) = v1;
    __syncthreads();

    s8v vprev[2][4];   // V fragments of tile kb, consumed by PV at kb+1 / epilogue

    for (int kb = 0; kb < nkb; kb++) {
        const bool more = (kb + 1 < nkb);
        if (more) {
            const size_t ko = (size_t)(kb + 1) * 64;
            k0 = *(const s8v*)(Kp + ko * Csz);
            k1 = *(const s8v*)(Kp + (ko + 32) * Csz);
            v0 = *(const s8v*)(Vp + ko);
            v1 = *(const s8v*)(Vp + ko + (size_t)32 * Tsz);
        }

        // K fragments (swizzled reads)
        s8v kf[2][4];
        #pragma unroll
        for (int nt = 0; nt < 4; nt++)
            #pragma unroll
            for (int kk = 0; kk < 2; kk++)
                kf[kk][nt] = *(const s8v*)(&Ksh[foff[kk][nt]]);

        // QK^T for tile kb
        f4v s[4];
        #pragma unroll
        for (int nt = 0; nt < 4; nt++) {
            #pragma unroll
            for (int i = 0; i < 4; i++) s[nt][i] = 0.f;
            s[nt] = __builtin_amdgcn_mfma_f32_16x16x32_bf16(kf[0][nt], qf[0], s[nt], 0, 0, 0);
            s[nt] = __builtin_amdgcn_mfma_f32_16x16x32_bf16(kf[1][nt], qf[1], s[nt], 0, 0, 0);
        }

        // PV for tile kb-1: P written a full iteration ago, latency expired
        if (kb > 0) {
            const short* Pr = Psh[(kb - 1) & 1][wave];
            const s8v pb0 = *(const s8v*)(Pr + ln * 72 + hi * 8);
            const s8v pb1 = *(const s8v*)(Pr + ln * 72 + 32 + hi * 8);
            #pragma unroll
            for (int dt = 0; dt < 4; dt++) {
                o[dt] = __builtin_amdgcn_mfma_f32_16x16x32_bf16(vprev[0][dt], pb0, o[dt], 0, 0, 0);
                o[dt] = __builtin_amdgcn_mfma_f32_16x16x32_bf16(vprev[1][dt], pb1, o[dt], 0, 0, 0);
            }
        }

        // exp + mask + pack -> write P(kb)  (v10 code, buffer kb&1)
        const bool dg = !more;   // kb == qt: diagonal block
        short* Pw = Psh[kb & 1][wave];
        #pragma unroll
        for (int nt = 0; nt < 4; nt++) {
            float pv[4];
            #pragma unroll
            for (int i = 0; i < 4; i++) pv[i] = exp2f(s[nt][i]);
            if (dg) {
                const int kr = nt * 16 + hi * 4;
                #pragma unroll
                for (int i = 0; i < 4; i++)
                    if (kr + i > qrel) pv[i] = 0.f;
            }
            lsum += (pv[0] + pv[1]) + (pv[2] + pv[3]);
            int2 w;
            w.x = (int)pack2_rn(pv[0], pv[1]);
            w.y = (int)pack2_rn(pv[2], pv[3]);
            *(int2*)(Pw + ln * 72 + nt * 16 + hi * 4) = w;  // ds_write_b64
        }

        // V fragments of tile kb -> registers (before LDS is overwritten)
        #pragma unroll
        for (int nt = 0; nt < 4; nt++)
            #pragma unroll
            for (int kk = 0; kk < 2; kk++)
                vprev[kk][nt] = *(const s8v*)(&Vsh[foff[kk][nt]]);

        if (more) {
            __syncthreads();                 // all waves done reading Ksh/Vsh
            *(s8v*)(&Ksh[swo]) = k0;         // vmcnt wait folds in here
            *(s8v*)(&Ksh[swo + 32 * 64]) = k1;
            *(s8v*)(&Vsh[swo]) = v0;
            *(s8v*)(&Vsh[swo + 32 * 64]) = v1;
            __syncthreads();                 // next tile ready
        }
    }

    // epilogue: PV for the last tile (nkb-1)
    {
        const short* Pr = Psh[(nkb - 1) & 1][wave];
        const s8v pb0 = *(const s8v*)(Pr + ln * 72 + hi * 8);
        const s8v pb1 = *(const s8v*)(Pr + ln * 72 + 32 + hi * 8);
        #pragma unroll
        for (int dt = 0; dt < 4; dt++) {
            o[dt] = __builtin_amdgcn_mfma_f32_16x16x32_bf16(vprev[0][dt], pb0, o[dt], 0, 0, 0);
            o[dt] = __builtin_amdgcn_mfma_f32_16x16x32_bf16(vprev[1][dt], pb1, o[dt], 0, 0, 0);
        }
    }

    // l = sum over all keys for q=ln: reduce across the 4 hi-groups (lanes ln+16k)
    float l = lsum;
    l += __shfl_xor(l, 16);
    l += __shfl_xor(l, 32);
    const float inv = 1.0f / l;
    const int qrow = qt * 64 + qrel;
    #pragma unroll
    for (int dt = 0; dt < 4; dt++) {
        int2 w;
        w.x = (int)pack2_rn(o[dt][0] * inv, o[dt][1] * inv);
        w.y = (int)pack2_rn(o[dt][2] * inv, o[dt][3] * inv);
        *(int2*)(Y + base + (size_t)qrow * Csz + dt * 16 + hi * 4) = w;
    }
}

extern "C" void kernel_launch(void* const* d_in, const int* in_sizes, int n_in,
                              void* d_out, int out_size, void* d_ws, size_t ws_size,
                              hipStream_t stream) {
    const float* x  = (const float*)d_in[0];
    const float* Wq = (const float*)d_in[1];
    const float* bq = (const float*)d_in[2];
    const float* Wk = (const float*)d_in[3];
    const float* bk = (const float*)d_in[4];
    const float* Wv = (const float*)d_in[5];
    const float* bv = (const float*)d_in[6];
    const float* Wp = (const float*)d_in[7];
    const float* bp = (const float*)d_in[8];

    char* ws = (char*)d_ws;
    short* Xb  = (short*)(ws);                 // 8 MB
    short* Wqb = (short*)(ws + (8u  << 20));   // 2 MB each
    short* Wkb = (short*)(ws + (10u << 20));
    short* Wvb = (short*)(ws + (12u << 20));
    short* Wpb = (short*)(ws + (14u << 20));
    short* Qb  = (short*)(ws + (16u << 20));   // 8 MB each
    short* Kb  = (short*)(ws + (24u << 20));
    short* Vtb = (short*)(ws + (32u << 20));   // V transposed per head [B*H*64, T]
    short* Yb  = (short*)(ws + (40u << 20));

    hipLaunchKernelGGL(cvt6, dim3(8192), dim3(256), 0, stream,
                       x, Wq, Wk, Wv, Wp, Xb, Wqb, Wkb, Wvb, Wpb);

    hipLaunchKernelGGL(qkv_gemm, dim3(32, 8, 3), dim3(256), 0, stream,
                       Xb, Wqb, Wkb, Wvb, bq, bk, bv, Qb, Kb, Vtb);

    hipLaunchKernelGGL(attn13, dim3(1024), dim3(256), 0, stream, Qb, Kb, Vtb, Yb);

    hipLaunchKernelGGL(proj_gemm, dim3(32, 16), dim3(256), 0, stream, Yb, Wpb, bp, (float*)d_out);
}

// Round 5
// 188.969 us; speedup vs baseline: 1.0402x; 1.0402x over previous
//
#include <hip/hip_runtime.h>
#include <hip/hip_bf16.h>

#define Tsz 2048
#define Csz 1024
#define Hn 16

typedef short s8v __attribute__((ext_vector_type(8)));
typedef short s4v __attribute__((ext_vector_type(4)));
typedef float f4v __attribute__((ext_vector_type(4)));
typedef int   i4v __attribute__((ext_vector_type(4)));
typedef unsigned u2v __attribute__((ext_vector_type(2)));

#define QSCALE (0.125f * 1.44269504088896f)  // 1/sqrt(64) * log2(e), folded into Q

// fast bf16 round (bits+0x8000)>>16 : 2 VALU vs ~6 for software RNE
__device__ __forceinline__ unsigned short bfr(float x) {
    return (unsigned short)((__builtin_bit_cast(unsigned, x) + 0x8000u) >> 16);
}
__device__ __forceinline__ unsigned pack2_rn(float a, float b) {
    const unsigned ua = __builtin_bit_cast(unsigned, a) + 0x8000u;
    const unsigned ub = __builtin_bit_cast(unsigned, b) + 0x8000u;
    return (ua >> 16) | (ub & 0xFFFF0000u);
}

__device__ __forceinline__ void gload_lds(const void* g, void* l) {
    __builtin_amdgcn_global_load_lds(
        (const __attribute__((address_space(1))) void*)g,
        (__attribute__((address_space(3))) void*)l, 16, 0, 0);
}

// ---------------- fp32 -> bf16 conversion, exact-size grid (8192 blocks) ----------------
__global__ void cvt6(const float* __restrict__ x, const float* __restrict__ wq,
                     const float* __restrict__ wk, const float* __restrict__ wv,
                     const float* __restrict__ wp,
                     short* __restrict__ xo, short* __restrict__ qo,
                     short* __restrict__ ko, short* __restrict__ vo,
                     short* __restrict__ po) {
    const int bx = blockIdx.x;
    const float* in; short* out; int ib;
    if (bx < 4096) { in = x; out = xo; ib = bx; }
    else {
        const int r = bx - 4096, w = r >> 10;
        ib = r & 1023;
        switch (w) {
            case 0: in = wq; out = qo; break;
            case 1: in = wk; out = ko; break;
            case 2: in = wv; out = vo; break;
            default: in = wp; out = po; break;
        }
    }
    const int i = ib * 1024 + threadIdx.x * 4;
    float4 v = *(const float4*)(in + i);
    int2 o;
    o.x = (int)pack2_rn(v.x, v.y);
    o.y = (int)pack2_rn(v.z, v.w);
    *(int2*)(out + i) = o;
}

// ---------------- fused QKV GEMM (m97 structure) ----------------
__global__ __launch_bounds__(256, 3) void qkv_gemm(
    const short* __restrict__ X,
    const short* __restrict__ Wq, const short* __restrict__ Wk, const short* __restrict__ Wv,
    const float* __restrict__ bq, const float* __restrict__ bk, const float* __restrict__ bv,
    short* __restrict__ Qo, short* __restrict__ Ko, short* __restrict__ Vto)
{
    const int z = blockIdx.z;
    const short* W = (z == 0) ? Wq : (z == 1) ? Wk : Wv;
    const float* bias = (z == 0) ? bq : (z == 1) ? bk : bv;

    __shared__ __align__(16) short Ash[128 * 32];
    __shared__ __align__(16) short Bsh[128 * 32];
    __shared__ __align__(16) short TR[64 * 72];   // transpose staging (z==2 epilogue)

    const int tid = threadIdx.x, lane = tid & 63, wave = tid >> 6;
    const int ln = lane & 15, hi = lane >> 4;
    const int m0 = blockIdx.x * 128, n0 = blockIdx.y * 128;
    const int wm = (wave >> 1) * 64, wn = (wave & 1) * 64;

    const short* Ag = X + (size_t)(m0 + (tid >> 2)) * Csz + (tid & 3) * 8;
    const short* Bg = W + (size_t)(n0 + (tid >> 2)) * Csz + (tid & 3) * 8;

    f4v acc[4][4];
    #pragma unroll
    for (int mt = 0; mt < 4; mt++)
        #pragma unroll
        for (int nt = 0; nt < 4; nt++)
            #pragma unroll
            for (int i = 0; i < 4; i++) acc[mt][nt][i] = 0.f;

    for (int k0 = 0; k0 < Csz; k0 += 32) {
        __syncthreads();
        gload_lds(Ag + k0, Ash + tid * 8);
        gload_lds(Ag + k0 + (size_t)64 * Csz, Ash + 2048 + tid * 8);
        gload_lds(Bg + k0, Bsh + tid * 8);
        gload_lds(Bg + k0 + (size_t)64 * Csz, Bsh + 2048 + tid * 8);
        __syncthreads();

        s8v af[4], bfr_[4];
        #pragma unroll
        for (int mt = 0; mt < 4; mt++)
            af[mt] = *(const s8v*)(Ash + (wm + mt * 16 + ln) * 32 + hi * 8);
        #pragma unroll
        for (int nt = 0; nt < 4; nt++)
            bfr_[nt] = *(const s8v*)(Bsh + (wn + nt * 16 + ln) * 32 + hi * 8);
        #pragma unroll
        for (int mt = 0; mt < 4; mt++)
            #pragma unroll
            for (int nt = 0; nt < 4; nt++)
                acc[mt][nt] = __builtin_amdgcn_mfma_f32_16x16x32_bf16(af[mt], bfr_[nt], acc[mt][nt], 0, 0, 0);
    }

    if (z == 2) {
        const int b = m0 >> 11, t0 = m0 & 2047;
        float bvv[4];
        #pragma unroll
        for (int nt = 0; nt < 4; nt++) bvv[nt] = bias[n0 + wn + nt * 16 + ln];
        #pragma unroll
        for (int ph = 0; ph < 4; ph++) {
            const int mh = ph >> 1, nh = ph & 1;
            __syncthreads();
            if ((wave >> 1) == mh && (wave & 1) == nh) {
                #pragma unroll
                for (int mt = 0; mt < 4; mt++)
                    #pragma unroll
                    for (int nt = 0; nt < 4; nt++) {
                        int2 pk;
                        pk.x = (int)pack2_rn(acc[mt][nt][0] + bvv[nt], acc[mt][nt][1] + bvv[nt]);
                        pk.y = (int)pack2_rn(acc[mt][nt][2] + bvv[nt], acc[mt][nt][3] + bvv[nt]);
                        *(int2*)(TR + (nt * 16 + ln) * 72 + mt * 16 + hi * 4) = pk;
                    }
            }
            __syncthreads();
            const int chl = tid >> 2, seg = tid & 3;
            const s8v r0 = *(const s8v*)(TR + chl * 72 + seg * 16);
            const s8v r1 = *(const s8v*)(TR + chl * 72 + seg * 16 + 8);
            short* dst = Vto + (size_t)(b * 1024 + n0 + nh * 64 + chl) * Tsz + t0 + mh * 64 + seg * 16;
            *(s8v*)(dst) = r0;
            *(s8v*)(dst + 8) = r1;
        }
        return;
    }

    const float scale = (z == 0) ? QSCALE : 1.0f;
    short* out = (z == 0) ? Qo : Ko;

    #pragma unroll
    for (int nt = 0; nt < 4; nt++) {
        const int col = n0 + wn + nt * 16 + ln;
        const float bvv = bias[col];
        #pragma unroll
        for (int mt = 0; mt < 4; mt++) {
            const int row0 = m0 + wm + mt * 16 + hi * 4;
            #pragma unroll
            for (int i = 0; i < 4; i++)
                out[(size_t)(row0 + i) * Csz + col] = (short)bfr((acc[mt][nt][i] + bvv) * scale);
        }
    }
}

// ---------------- output projection GEMM (f32 out), 128x64 tiles, grid (32,16) ----------------
__global__ __launch_bounds__(256, 2) void proj_gemm(
    const short* __restrict__ A, const short* __restrict__ W,
    const float* __restrict__ bias, float* __restrict__ out)
{
    __shared__ __align__(16) short Ash[128 * 32];
    __shared__ __align__(16) short Bsh[64 * 32];

    const int tid = threadIdx.x, lane = tid & 63, wave = tid >> 6;
    const int ln = lane & 15, hi = lane >> 4;
    const int m0 = blockIdx.x * 128, n0 = blockIdx.y * 64;
    const int wm = (wave >> 1) * 64, wn = (wave & 1) * 32;

    const short* Ag = A + (size_t)(m0 + (tid >> 2)) * Csz + (tid & 3) * 8;
    const short* Bg = W + (size_t)(n0 + (tid >> 2)) * Csz + (tid & 3) * 8;

    f4v acc[4][2];
    #pragma unroll
    for (int mt = 0; mt < 4; mt++)
        #pragma unroll
        for (int nt = 0; nt < 2; nt++)
            #pragma unroll
            for (int i = 0; i < 4; i++) acc[mt][nt][i] = 0.f;

    for (int k0 = 0; k0 < Csz; k0 += 32) {
        __syncthreads();
        gload_lds(Ag + k0, Ash + tid * 8);
        gload_lds(Ag + k0 + (size_t)64 * Csz, Ash + 2048 + tid * 8);
        gload_lds(Bg + k0, Bsh + tid * 8);
        __syncthreads();

        s8v af[4], bfr_[2];
        #pragma unroll
        for (int mt = 0; mt < 4; mt++)
            af[mt] = *(const s8v*)(Ash + (wm + mt * 16 + ln) * 32 + hi * 8);
        #pragma unroll
        for (int nt = 0; nt < 2; nt++)
            bfr_[nt] = *(const s8v*)(Bsh + (wn + nt * 16 + ln) * 32 + hi * 8);
        #pragma unroll
        for (int mt = 0; mt < 4; mt++)
            #pragma unroll
            for (int nt = 0; nt < 2; nt++)
                acc[mt][nt] = __builtin_amdgcn_mfma_f32_16x16x32_bf16(af[mt], bfr_[nt], acc[mt][nt], 0, 0, 0);
    }

    #pragma unroll
    for (int nt = 0; nt < 2; nt++) {
        const int col = n0 + wn + nt * 16 + ln;
        const float bvv = bias[col];
        #pragma unroll
        for (int mt = 0; mt < 4; mt++)
            #pragma unroll
            for (int i = 0; i < 4; i++)
                out[(size_t)(m0 + wm + mt * 16 + hi * 4 + i) * Csz + col] = acc[mt][nt][i] + bvv;
    }
}

// ---------------- Flash attention v14: v10 base + swizzled K/V + builtin permlane P ----------------
// Base: v10 (green). Changes:
//  (1) [v13-verified] K/V LDS pitch 64 shorts with 16B-slot XOR swizzle (slot^=row&7),
//      same swizzle on staging write and fragment read. Conflicts 5.95M -> 1.6M measured.
//  (2) P^T C-layout -> PV B-fragment redistribution done IN REGISTERS via the gfx950
//      permlane-swap BUILTINS (compiler handles the VALU->permlane wait-state hazard
//      that plausibly broke the v11/v12 inline-asm attempts):
//        permlane32_swap: VDST rows2,3 <-> SRC rows0,1 (row = 16 lanes)
//        permlane16_swap: VDST rows1,3 <-> SRC rows0,2
//      With A=w[nt_even], B=w[nt_odd]:  swap32 then swap16 gives
//        A'' = [A@r0, A@r2, B@r0, B@r2]  (B-frag words at j-pair hi)
//        B'' = [A@r1, A@r3, B@r1, B@r3]  (B-frag words at j-pair 2+hi)
//      8 VALU ops replace 4 ds_write_b64 + lgkmcnt(0) + 2 ds_read_b128 per wave-tile,
//      cutting ~250-300 cyc off the per-tile serial chain (the measured limiter:
//      264 wave-tile-units/CU at a concurrency-independent ~486 cyc/unit).
//      Psh deleted: LDS 27.6 -> 16.4 KB.
__global__ __launch_bounds__(256, 4) void attn14(
    const short* __restrict__ Q, const short* __restrict__ Kg,
    const short* __restrict__ Vt, short* __restrict__ Y)
{
    __shared__ __align__(16) short Ksh[64 * 64];      // [key][slot-swizzled d], pitch 64
    __shared__ __align__(16) short Vsh[64 * 64];      // [d][slot-swizzled key], pitch 64

    const int tid = threadIdx.x, lane = tid & 63, wave = tid >> 6;
    const int ln = lane & 15, hi = lane >> 4;

    // block -> (q-tile, head): v10 mapping (verified green)
    const int n = blockIdx.x;
    const int c = n & 255, j = n >> 8;
    const int bh = (j << 3) | (c >> 5);               // 0..31
    const int t = c & 31;
    const int qt = (j & 1) ? t : 31 - t;              // q-tile index 0..31

    const size_t base = (size_t)(bh >> 4) * Tsz * Csz + (size_t)(bh & 15) * 64;
    const size_t vtbase = (size_t)bh * 64 * Tsz;
    const int qrel = wave * 16 + ln;                  // within-tile q row (MFMA n-col)

    s8v qf[2];
    #pragma unroll
    for (int kk = 0; kk < 2; kk++)
        qf[kk] = *(const s8v*)(Q + base + (size_t)(qt * 64 + qrel) * Csz + kk * 32 + hi * 8);

    f4v o[4];
    float lsum = 0.f;
    #pragma unroll
    for (int dt = 0; dt < 4; dt++)
        #pragma unroll
        for (int i = 0; i < 4; i++) o[dt][i] = 0.f;

    // staging: 256 threads, each 2x16B of K and 2x16B of V per tile; rows sr / sr+32
    // share (sr&7) so one swizzled offset serves both.
    const int sr = tid >> 3, scs = tid & 7;
    const short* Kp = Kg + base + (size_t)sr * Csz + scs * 8;
    const short* Vp = Vt + vtbase + (size_t)sr * Tsz + scs * 8;
    const int swo = sr * 64 + (scs ^ (sr & 7)) * 8;
    const int nkb = qt + 1;                           // exactly the causal tiles

    // fragment-read offsets (row = nt*16+ln, slot = kk*4+hi, swizzle by ln&7)
    int foff[2][4];
    #pragma unroll
    for (int nt = 0; nt < 4; nt++)
        #pragma unroll
        for (int kk = 0; kk < 2; kk++)
            foff[kk][nt] = (nt * 16 + ln) * 64 + (((kk * 4 + hi) ^ (ln & 7)) * 8);

    // prologue: tile 0 -> LDS
    s8v k0 = *(const s8v*)(Kp);
    s8v k1 = *(const s8v*)(Kp + (size_t)32 * Csz);
    s8v v0 = *(const s8v*)(Vp);
    s8v v1 = *(const s8v*)(Vp + (size_t)32 * Tsz);
    *(s8v*)(&Ksh[swo]) = k0;
    *(s8v*)(&Ksh[swo + 32 * 64]) = k1;
    *(s8v*)(&Vsh[swo]) = v0;
    *(s8v*)(&Vsh[swo + 32 * 64]) = v1;
    __syncthreads();

    for (int kb = 0; kb < nkb; kb++) {
        const bool more = (kb + 1 < nkb);
        if (more) {
            const size_t ko = (size_t)(kb + 1) * 64;
            k0 = *(const s8v*)(Kp + ko * Csz);
            k1 = *(const s8v*)(Kp + (ko + 32) * Csz);
            v0 = *(const s8v*)(Vp + ko);
            v1 = *(const s8v*)(Vp + ko + (size_t)32 * Tsz);
        }

        s8v kf[2][4], vf[2][4];
        #pragma unroll
        for (int nt = 0; nt < 4; nt++)
            #pragma unroll
            for (int kk = 0; kk < 2; kk++) {
                kf[kk][nt] = *(const s8v*)(&Ksh[foff[kk][nt]]);
                vf[kk][nt] = *(const s8v*)(&Vsh[foff[kk][nt]]);
            }

        // QK^T for tile kb: lane holds S[key = nt*16+hi*4+i][q = ln]
        f4v s[4];
        #pragma unroll
        for (int nt = 0; nt < 4; nt++) {
            #pragma unroll
            for (int i = 0; i < 4; i++) s[nt][i] = 0.f;
            s[nt] = __builtin_amdgcn_mfma_f32_16x16x32_bf16(kf[0][nt], qf[0], s[nt], 0, 0, 0);
            s[nt] = __builtin_amdgcn_mfma_f32_16x16x32_bf16(kf[1][nt], qf[1], s[nt], 0, 0, 0);
        }

        // exp + mask + pack: pw[nt][w] = bf16 pair (keys nt*16+hi*4+2w, +2w+1), q=ln
        const bool dg = !more;   // kb == qt: diagonal block
        unsigned pw[4][2];
        #pragma unroll
        for (int nt = 0; nt < 4; nt++) {
            float pv[4];
            #pragma unroll
            for (int i = 0; i < 4; i++) pv[i] = exp2f(s[nt][i]);
            if (dg) {
                const int kr = nt * 16 + hi * 4;
                #pragma unroll
                for (int i = 0; i < 4; i++)
                    if (kr + i > qrel) pv[i] = 0.f;
            }
            lsum += (pv[0] + pv[1]) + (pv[2] + pv[3]);
            pw[nt][0] = pack2_rn(pv[0], pv[1]);
            pw[nt][1] = pack2_rn(pv[2], pv[3]);
        }

        // in-register C-layout -> B-frag redistribution (builtin permlane swaps)
        u2v r0a = __builtin_amdgcn_permlane32_swap(pw[0][0], pw[1][0], false, false);
        u2v r0b = __builtin_amdgcn_permlane16_swap(r0a[0], r0a[1], false, false);
        u2v r1a = __builtin_amdgcn_permlane32_swap(pw[0][1], pw[1][1], false, false);
        u2v r1b = __builtin_amdgcn_permlane16_swap(r1a[0], r1a[1], false, false);
        u2v r2a = __builtin_amdgcn_permlane32_swap(pw[2][0], pw[3][0], false, false);
        u2v r2b = __builtin_amdgcn_permlane16_swap(r2a[0], r2a[1], false, false);
        u2v r3a = __builtin_amdgcn_permlane32_swap(pw[2][1], pw[3][1], false, false);
        u2v r3b = __builtin_amdgcn_permlane16_swap(r3a[0], r3a[1], false, false);
        i4v p0 = { (int)r0b[0], (int)r1b[0], (int)r0b[1], (int)r1b[1] };
        i4v p1 = { (int)r2b[0], (int)r3b[0], (int)r2b[1], (int)r3b[1] };
        const s8v pb0 = __builtin_bit_cast(s8v, p0);
        const s8v pb1 = __builtin_bit_cast(s8v, p1);

        #pragma unroll
        for (int dt = 0; dt < 4; dt++) {
            o[dt] = __builtin_amdgcn_mfma_f32_16x16x32_bf16(vf[0][dt], pb0, o[dt], 0, 0, 0);
            o[dt] = __builtin_amdgcn_mfma_f32_16x16x32_bf16(vf[1][dt], pb1, o[dt], 0, 0, 0);
        }

        if (more) {
            __syncthreads();                 // all waves done reading Ksh/Vsh
            *(s8v*)(&Ksh[swo]) = k0;         // vmcnt wait folds in here
            *(s8v*)(&Ksh[swo + 32 * 64]) = k1;
            *(s8v*)(&Vsh[swo]) = v0;
            *(s8v*)(&Vsh[swo + 32 * 64]) = v1;
            __syncthreads();                 // next tile ready
        }
    }

    // l = sum over all keys for q=ln: reduce across the 4 hi-groups (lanes ln+16k)
    float l = lsum;
    l += __shfl_xor(l, 16);
    l += __shfl_xor(l, 32);
    const float inv = 1.0f / l;
    const int qrow = qt * 64 + qrel;
    #pragma unroll
    for (int dt = 0; dt < 4; dt++) {
        int2 w;
        w.x = (int)pack2_rn(o[dt][0] * inv, o[dt][1] * inv);
        w.y = (int)pack2_rn(o[dt][2] * inv, o[dt][3] * inv);
        *(int2*)(Y + base + (size_t)qrow * Csz + dt * 16 + hi * 4) = w;
    }
}

extern "C" void kernel_launch(void* const* d_in, const int* in_sizes, int n_in,
                              void* d_out, int out_size, void* d_ws, size_t ws_size,
                              hipStream_t stream) {
    const float* x  = (const float*)d_in[0];
    const float* Wq = (const float*)d_in[1];
    const float* bq = (const float*)d_in[2];
    const float* Wk = (const float*)d_in[3];
    const float* bk = (const float*)d_in[4];
    const float* Wv = (const float*)d_in[5];
    const float* bv = (const float*)d_in[6];
    const float* Wp = (const float*)d_in[7];
    const float* bp = (const float*)d_in[8];

    char* ws = (char*)d_ws;
    short* Xb  = (short*)(ws);                 // 8 MB
    short* Wqb = (short*)(ws + (8u  << 20));   // 2 MB each
    short* Wkb = (short*)(ws + (10u << 20));
    short* Wvb = (short*)(ws + (12u << 20));
    short* Wpb = (short*)(ws + (14u << 20));
    short* Qb  = (short*)(ws + (16u << 20));   // 8 MB each
    short* Kb  = (short*)(ws + (24u << 20));
    short* Vtb = (short*)(ws + (32u << 20));   // V transposed per head [B*H*64, T]
    short* Yb  = (short*)(ws + (40u << 20));

    hipLaunchKernelGGL(cvt6, dim3(8192), dim3(256), 0, stream,
                       x, Wq, Wk, Wv, Wp, Xb, Wqb, Wkb, Wvb, Wpb);

    hipLaunchKernelGGL(qkv_gemm, dim3(32, 8, 3), dim3(256), 0, stream,
                       Xb, Wqb, Wkb, Wvb, bq, bk, bv, Qb, Kb, Vtb);

    hipLaunchKernelGGL(attn14, dim3(1024), dim3(256), 0, stream, Qb, Kb, Vtb, Yb);

    hipLaunchKernelGGL(proj_gemm, dim3(32, 16), dim3(256), 0, stream, Yb, Wpb, bp, (float*)d_out);
}

// Round 6
// 186.499 us; speedup vs baseline: 1.0540x; 1.0132x over previous
//
#include <hip/hip_runtime.h>
#include <hip/hip_bf16.h>

#define Tsz 2048
#define Csz 1024
#define Hn 16

typedef short s8v __attribute__((ext_vector_type(8)));
typedef short s4v __attribute__((ext_vector_type(4)));
typedef float f4v __attribute__((ext_vector_type(4)));
typedef int   i4v __attribute__((ext_vector_type(4)));
typedef unsigned u2v __attribute__((ext_vector_type(2)));

#define QSCALE (0.125f * 1.44269504088896f)  // 1/sqrt(64) * log2(e), folded into Q

// fast bf16 round (bits+0x8000)>>16 : 2 VALU vs ~6 for software RNE
__device__ __forceinline__ unsigned short bfr(float x) {
    return (unsigned short)((__builtin_bit_cast(unsigned, x) + 0x8000u) >> 16);
}
__device__ __forceinline__ unsigned pack2_rn(float a, float b) {
    const unsigned ua = __builtin_bit_cast(unsigned, a) + 0x8000u;
    const unsigned ub = __builtin_bit_cast(unsigned, b) + 0x8000u;
    return (ua >> 16) | (ub & 0xFFFF0000u);
}

__device__ __forceinline__ void gload_lds(const void* g, void* l) {
    __builtin_amdgcn_global_load_lds(
        (const __attribute__((address_space(1))) void*)g,
        (__attribute__((address_space(3))) void*)l, 16, 0, 0);
}

// ---------------- fp32 -> bf16 conversion, exact-size grid (8192 blocks) ----------------
__global__ void cvt6(const float* __restrict__ x, const float* __restrict__ wq,
                     const float* __restrict__ wk, const float* __restrict__ wv,
                     const float* __restrict__ wp,
                     short* __restrict__ xo, short* __restrict__ qo,
                     short* __restrict__ ko, short* __restrict__ vo,
                     short* __restrict__ po) {
    const int bx = blockIdx.x;
    const float* in; short* out; int ib;
    if (bx < 4096) { in = x; out = xo; ib = bx; }
    else {
        const int r = bx - 4096, w = r >> 10;
        ib = r & 1023;
        switch (w) {
            case 0: in = wq; out = qo; break;
            case 1: in = wk; out = ko; break;
            case 2: in = wv; out = vo; break;
            default: in = wp; out = po; break;
        }
    }
    const int i = ib * 1024 + threadIdx.x * 4;
    float4 v = *(const float4*)(in + i);
    int2 o;
    o.x = (int)pack2_rn(v.x, v.y);
    o.y = (int)pack2_rn(v.z, v.w);
    *(int2*)(out + i) = o;
}

// ---------------- fused QKV GEMM (m97 structure) ----------------
__global__ __launch_bounds__(256, 3) void qkv_gemm(
    const short* __restrict__ X,
    const short* __restrict__ Wq, const short* __restrict__ Wk, const short* __restrict__ Wv,
    const float* __restrict__ bq, const float* __restrict__ bk, const float* __restrict__ bv,
    short* __restrict__ Qo, short* __restrict__ Ko, short* __restrict__ Vto)
{
    const int z = blockIdx.z;
    const short* W = (z == 0) ? Wq : (z == 1) ? Wk : Wv;
    const float* bias = (z == 0) ? bq : (z == 1) ? bk : bv;

    __shared__ __align__(16) short Ash[128 * 32];
    __shared__ __align__(16) short Bsh[128 * 32];
    __shared__ __align__(16) short TR[64 * 72];   // transpose staging (z==2 epilogue)

    const int tid = threadIdx.x, lane = tid & 63, wave = tid >> 6;
    const int ln = lane & 15, hi = lane >> 4;
    const int m0 = blockIdx.x * 128, n0 = blockIdx.y * 128;
    const int wm = (wave >> 1) * 64, wn = (wave & 1) * 64;

    const short* Ag = X + (size_t)(m0 + (tid >> 2)) * Csz + (tid & 3) * 8;
    const short* Bg = W + (size_t)(n0 + (tid >> 2)) * Csz + (tid & 3) * 8;

    f4v acc[4][4];
    #pragma unroll
    for (int mt = 0; mt < 4; mt++)
        #pragma unroll
        for (int nt = 0; nt < 4; nt++)
            #pragma unroll
            for (int i = 0; i < 4; i++) acc[mt][nt][i] = 0.f;

    for (int k0 = 0; k0 < Csz; k0 += 32) {
        __syncthreads();
        gload_lds(Ag + k0, Ash + tid * 8);
        gload_lds(Ag + k0 + (size_t)64 * Csz, Ash + 2048 + tid * 8);
        gload_lds(Bg + k0, Bsh + tid * 8);
        gload_lds(Bg + k0 + (size_t)64 * Csz, Bsh + 2048 + tid * 8);
        __syncthreads();

        s8v af[4], bfr_[4];
        #pragma unroll
        for (int mt = 0; mt < 4; mt++)
            af[mt] = *(const s8v*)(Ash + (wm + mt * 16 + ln) * 32 + hi * 8);
        #pragma unroll
        for (int nt = 0; nt < 4; nt++)
            bfr_[nt] = *(const s8v*)(Bsh + (wn + nt * 16 + ln) * 32 + hi * 8);
        #pragma unroll
        for (int mt = 0; mt < 4; mt++)
            #pragma unroll
            for (int nt = 0; nt < 4; nt++)
                acc[mt][nt] = __builtin_amdgcn_mfma_f32_16x16x32_bf16(af[mt], bfr_[nt], acc[mt][nt], 0, 0, 0);
    }

    if (z == 2) {
        const int b = m0 >> 11, t0 = m0 & 2047;
        float bvv[4];
        #pragma unroll
        for (int nt = 0; nt < 4; nt++) bvv[nt] = bias[n0 + wn + nt * 16 + ln];
        #pragma unroll
        for (int ph = 0; ph < 4; ph++) {
            const int mh = ph >> 1, nh = ph & 1;
            __syncthreads();
            if ((wave >> 1) == mh && (wave & 1) == nh) {
                #pragma unroll
                for (int mt = 0; mt < 4; mt++)
                    #pragma unroll
                    for (int nt = 0; nt < 4; nt++) {
                        int2 pk;
                        pk.x = (int)pack2_rn(acc[mt][nt][0] + bvv[nt], acc[mt][nt][1] + bvv[nt]);
                        pk.y = (int)pack2_rn(acc[mt][nt][2] + bvv[nt], acc[mt][nt][3] + bvv[nt]);
                        *(int2*)(TR + (nt * 16 + ln) * 72 + mt * 16 + hi * 4) = pk;
                    }
            }
            __syncthreads();
            const int chl = tid >> 2, seg = tid & 3;
            const s8v r0 = *(const s8v*)(TR + chl * 72 + seg * 16);
            const s8v r1 = *(const s8v*)(TR + chl * 72 + seg * 16 + 8);
            short* dst = Vto + (size_t)(b * 1024 + n0 + nh * 64 + chl) * Tsz + t0 + mh * 64 + seg * 16;
            *(s8v*)(dst) = r0;
            *(s8v*)(dst + 8) = r1;
        }
        return;
    }

    const float scale = (z == 0) ? QSCALE : 1.0f;
    short* out = (z == 0) ? Qo : Ko;

    #pragma unroll
    for (int nt = 0; nt < 4; nt++) {
        const int col = n0 + wn + nt * 16 + ln;
        const float bvv = bias[col];
        #pragma unroll
        for (int mt = 0; mt < 4; mt++) {
            const int row0 = m0 + wm + mt * 16 + hi * 4;
            #pragma unroll
            for (int i = 0; i < 4; i++)
                out[(size_t)(row0 + i) * Csz + col] = (short)bfr((acc[mt][nt][i] + bvv) * scale);
        }
    }
}

// ---------------- output projection GEMM (f32 out), 128x64 tiles, grid (32,16) ----------------
__global__ __launch_bounds__(256, 2) void proj_gemm(
    const short* __restrict__ A, const short* __restrict__ W,
    const float* __restrict__ bias, float* __restrict__ out)
{
    __shared__ __align__(16) short Ash[128 * 32];
    __shared__ __align__(16) short Bsh[64 * 32];

    const int tid = threadIdx.x, lane = tid & 63, wave = tid >> 6;
    const int ln = lane & 15, hi = lane >> 4;
    const int m0 = blockIdx.x * 128, n0 = blockIdx.y * 64;
    const int wm = (wave >> 1) * 64, wn = (wave & 1) * 32;

    const short* Ag = A + (size_t)(m0 + (tid >> 2)) * Csz + (tid & 3) * 8;
    const short* Bg = W + (size_t)(n0 + (tid >> 2)) * Csz + (tid & 3) * 8;

    f4v acc[4][2];
    #pragma unroll
    for (int mt = 0; mt < 4; mt++)
        #pragma unroll
        for (int nt = 0; nt < 2; nt++)
            #pragma unroll
            for (int i = 0; i < 4; i++) acc[mt][nt][i] = 0.f;

    for (int k0 = 0; k0 < Csz; k0 += 32) {
        __syncthreads();
        gload_lds(Ag + k0, Ash + tid * 8);
        gload_lds(Ag + k0 + (size_t)64 * Csz, Ash + 2048 + tid * 8);
        gload_lds(Bg + k0, Bsh + tid * 8);
        __syncthreads();

        s8v af[4], bfr_[2];
        #pragma unroll
        for (int mt = 0; mt < 4; mt++)
            af[mt] = *(const s8v*)(Ash + (wm + mt * 16 + ln) * 32 + hi * 8);
        #pragma unroll
        for (int nt = 0; nt < 2; nt++)
            bfr_[nt] = *(const s8v*)(Bsh + (wn + nt * 16 + ln) * 32 + hi * 8);
        #pragma unroll
        for (int mt = 0; mt < 4; mt++)
            #pragma unroll
            for (int nt = 0; nt < 2; nt++)
                acc[mt][nt] = __builtin_amdgcn_mfma_f32_16x16x32_bf16(af[mt], bfr_[nt], acc[mt][nt], 0, 0, 0);
    }

    #pragma unroll
    for (int nt = 0; nt < 2; nt++) {
        const int col = n0 + wn + nt * 16 + ln;
        const float bvv = bias[col];
        #pragma unroll
        for (int mt = 0; mt < 4; mt++)
            #pragma unroll
            for (int i = 0; i < 4; i++)
                out[(size_t)(m0 + wm + mt * 16 + hi * 4 + i) * Csz + col] = acc[mt][nt][i] + bvv;
    }
}

// ---------------- Flash attention v15: v14 core + DMA triple-buffer + counted vmcnt ----------------
// v14 compute core (green: permlane P, zero-conflict swizzle) unchanged.
// Staging rebuilt as T3+T4: global_load_lds DMA into 3 K/V buffers, issued 2 tiles
// ahead, drained with counted s_waitcnt vmcnt(4) + raw s_barrier (ONE per tile,
// no full vmcnt(0)/lgkmcnt(0) drain). Load-latency window ~= 2 compute phases.
// Swizzle preserved under DMA's linear-dest rule by PRE-SWIZZLING the global
// source: stager of LDS slot s, row r fetches global col-slot s^(r&7) -> LDS
// image identical to v14's, so fragment reads (foff) are unchanged.
// vmcnt audit: prologue {2 qf + 4 t0 [+ 4 t1]} -> wait 4 (or 0);
// steady {4 t(kb+1) + 4 t(kb+2)} -> wait 4; tail -> wait 0; last iter: none.
__global__ __launch_bounds__(256, 3) void attn15(
    const short* __restrict__ Q, const short* __restrict__ Kg,
    const short* __restrict__ Vt, short* __restrict__ Y)
{
    __shared__ __align__(16) short SB[3][2][64 * 64];   // [buf][K/V][row][slot-swizzled 16B slots]

    const int tid = threadIdx.x, lane = tid & 63, wave = tid >> 6;
    const int ln = lane & 15, hi = lane >> 4;

    // block -> (q-tile, head): v10 mapping (verified green)
    const int n = blockIdx.x;
    const int c = n & 255, j = n >> 8;
    const int bh = (j << 3) | (c >> 5);               // 0..31
    const int t = c & 31;
    const int qt = (j & 1) ? t : 31 - t;              // q-tile index 0..31

    const size_t base = (size_t)(bh >> 4) * Tsz * Csz + (size_t)(bh & 15) * 64;
    const size_t vtbase = (size_t)bh * 64 * Tsz;
    const int qrel = wave * 16 + ln;                  // within-tile q row (MFMA n-col)

    s8v qf[2];
    #pragma unroll
    for (int kk = 0; kk < 2; kk++)
        qf[kk] = *(const s8v*)(Q + base + (size_t)(qt * 64 + qrel) * Csz + kk * 32 + hi * 8);

    f4v o[4];
    float lsum = 0.f;
    #pragma unroll
    for (int dt = 0; dt < 4; dt++)
        #pragma unroll
        for (int i = 0; i < 4; i++) o[dt][i] = 0.f;

    // DMA staging: thread t covers rows sr / sr+32, LDS slot scs (linear dest
    // tid*16B); global col-slot pre-swizzled: scs ^ (sr&7). (sr+32)&7 == sr&7.
    const int sr = tid >> 3, scs = tid & 7;
    const int csw = (scs ^ (sr & 7)) * 8;             // pre-swizzled col offset (shorts)
    const short* KpA = Kg + base + (size_t)sr * Csz + csw;
    const short* KpB = KpA + (size_t)32 * Csz;
    const short* VpA = Vt + vtbase + (size_t)sr * Tsz + csw;
    const short* VpB = VpA + (size_t)32 * Tsz;
    const int nkb = qt + 1;                           // exactly the causal tiles

    // fragment-read offsets (row = nt*16+ln, slot = kk*4+hi, swizzle by ln&7) — v14-green
    int foff[2][4];
    #pragma unroll
    for (int nt = 0; nt < 4; nt++)
        #pragma unroll
        for (int kk = 0; kk < 2; kk++)
            foff[kk][nt] = (nt * 16 + ln) * 64 + (((kk * 4 + hi) ^ (ln & 7)) * 8);

    #define STAGE(b, kb_) {                                              \
        const size_t ko_ = (size_t)(kb_) * 64;                           \
        gload_lds(KpA + ko_ * Csz, &SB[b][0][tid * 8]);                  \
        gload_lds(KpB + ko_ * Csz, &SB[b][0][2048 + tid * 8]);           \
        gload_lds(VpA + ko_,       &SB[b][1][tid * 8]);                  \
        gload_lds(VpB + ko_,       &SB[b][1][2048 + tid * 8]);           \
    }

    // prologue: tiles 0 (and 1) in flight; wait tile 0 only
    STAGE(0, 0);
    if (nkb > 1) {
        STAGE(1, 1);
        asm volatile("s_waitcnt vmcnt(4)" ::: "memory");
    } else {
        asm volatile("s_waitcnt vmcnt(0)" ::: "memory");
    }
    __builtin_amdgcn_s_barrier();

    int bcur = 0, bnext = 1, bnn = 2;
    for (int kb = 0; kb < nkb; kb++) {
        if (kb + 2 < nkb) STAGE(bnn, kb + 2);        // overwrites tile kb-1's buf (reads barrier'd)

        const short* Kl = SB[bcur][0];
        const short* Vl = SB[bcur][1];
        s8v kf[2][4], vf[2][4];
        #pragma unroll
        for (int nt = 0; nt < 4; nt++)
            #pragma unroll
            for (int kk = 0; kk < 2; kk++) {
                kf[kk][nt] = *(const s8v*)(&Kl[foff[kk][nt]]);
                vf[kk][nt] = *(const s8v*)(&Vl[foff[kk][nt]]);
            }

        // QK^T for tile kb: lane holds S[key = nt*16+hi*4+i][q = ln]
        f4v s[4];
        #pragma unroll
        for (int nt = 0; nt < 4; nt++) {
            #pragma unroll
            for (int i = 0; i < 4; i++) s[nt][i] = 0.f;
            s[nt] = __builtin_amdgcn_mfma_f32_16x16x32_bf16(kf[0][nt], qf[0], s[nt], 0, 0, 0);
            s[nt] = __builtin_amdgcn_mfma_f32_16x16x32_bf16(kf[1][nt], qf[1], s[nt], 0, 0, 0);
        }

        // exp + mask + pack
        const bool dg = (kb == qt);
        unsigned pw[4][2];
        #pragma unroll
        for (int nt = 0; nt < 4; nt++) {
            float pv[4];
            #pragma unroll
            for (int i = 0; i < 4; i++) pv[i] = exp2f(s[nt][i]);
            if (dg) {
                const int kr = nt * 16 + hi * 4;
                #pragma unroll
                for (int i = 0; i < 4; i++)
                    if (kr + i > qrel) pv[i] = 0.f;
            }
            lsum += (pv[0] + pv[1]) + (pv[2] + pv[3]);
            pw[nt][0] = pack2_rn(pv[0], pv[1]);
            pw[nt][1] = pack2_rn(pv[2], pv[3]);
        }

        // in-register C-layout -> B-frag redistribution (builtin permlane swaps, v14-green)
        u2v r0a = __builtin_amdgcn_permlane32_swap(pw[0][0], pw[1][0], false, false);
        u2v r0b = __builtin_amdgcn_permlane16_swap(r0a[0], r0a[1], false, false);
        u2v r1a = __builtin_amdgcn_permlane32_swap(pw[0][1], pw[1][1], false, false);
        u2v r1b = __builtin_amdgcn_permlane16_swap(r1a[0], r1a[1], false, false);
        u2v r2a = __builtin_amdgcn_permlane32_swap(pw[2][0], pw[3][0], false, false);
        u2v r2b = __builtin_amdgcn_permlane16_swap(r2a[0], r2a[1], false, false);
        u2v r3a = __builtin_amdgcn_permlane32_swap(pw[2][1], pw[3][1], false, false);
        u2v r3b = __builtin_amdgcn_permlane16_swap(r3a[0], r3a[1], false, false);
        i4v p0 = { (int)r0b[0], (int)r1b[0], (int)r0b[1], (int)r1b[1] };
        i4v p1 = { (int)r2b[0], (int)r3b[0], (int)r2b[1], (int)r3b[1] };
        const s8v pb0 = __builtin_bit_cast(s8v, p0);
        const s8v pb1 = __builtin_bit_cast(s8v, p1);

        #pragma unroll
        for (int dt = 0; dt < 4; dt++) {
            o[dt] = __builtin_amdgcn_mfma_f32_16x16x32_bf16(vf[0][dt], pb0, o[dt], 0, 0, 0);
            o[dt] = __builtin_amdgcn_mfma_f32_16x16x32_bf16(vf[1][dt], pb1, o[dt], 0, 0, 0);
        }

        if (kb + 1 < nkb) {
            if (kb + 2 < nkb) asm volatile("s_waitcnt vmcnt(4)" ::: "memory");
            else              asm volatile("s_waitcnt vmcnt(0)" ::: "memory");
            __builtin_amdgcn_s_barrier();            // raw: no full drain
        }
        const int tb = bcur; bcur = bnext; bnext = bnn; bnn = tb;
    }
    #undef STAGE

    // l = sum over all keys for q=ln: reduce across the 4 hi-groups (lanes ln+16k)
    float l = lsum;
    l += __shfl_xor(l, 16);
    l += __shfl_xor(l, 32);
    const float inv = 1.0f / l;
    const int qrow = qt * 64 + qrel;
    #pragma unroll
    for (int dt = 0; dt < 4; dt++) {
        int2 w;
        w.x = (int)pack2_rn(o[dt][0] * inv, o[dt][1] * inv);
        w.y = (int)pack2_rn(o[dt][2] * inv, o[dt][3] * inv);
        *(int2*)(Y + base + (size_t)qrow * Csz + dt * 16 + hi * 4) = w;
    }
}

extern "C" void kernel_launch(void* const* d_in, const int* in_sizes, int n_in,
                              void* d_out, int out_size, void* d_ws, size_t ws_size,
                              hipStream_t stream) {
    const float* x  = (const float*)d_in[0];
    const float* Wq = (const float*)d_in[1];
    const float* bq = (const float*)d_in[2];
    const float* Wk = (const float*)d_in[3];
    const float* bk = (const float*)d_in[4];
    const float* Wv = (const float*)d_in[5];
    const float* bv = (const float*)d_in[6];
    const float* Wp = (const float*)d_in[7];
    const float* bp = (const float*)d_in[8];

    char* ws = (char*)d_ws;
    short* Xb  = (short*)(ws);                 // 8 MB
    short* Wqb = (short*)(ws + (8u  << 20));   // 2 MB each
    short* Wkb = (short*)(ws + (10u << 20));
    short* Wvb = (short*)(ws + (12u << 20));
    short* Wpb = (short*)(ws + (14u << 20));
    short* Qb  = (short*)(ws + (16u << 20));   // 8 MB each
    short* Kb  = (short*)(ws + (24u << 20));
    short* Vtb = (short*)(ws + (32u << 20));   // V transposed per head [B*H*64, T]
    short* Yb  = (short*)(ws + (40u << 20));

    hipLaunchKernelGGL(cvt6, dim3(8192), dim3(256), 0, stream,
                       x, Wq, Wk, Wv, Wp, Xb, Wqb, Wkb, Wvb, Wpb);

    hipLaunchKernelGGL(qkv_gemm, dim3(32, 8, 3), dim3(256), 0, stream,
                       Xb, Wqb, Wkb, Wvb, bq, bk, bv, Qb, Kb, Vtb);

    hipLaunchKernelGGL(attn15, dim3(1024), dim3(256), 0, stream, Qb, Kb, Vtb, Yb);

    hipLaunchKernelGGL(proj_gemm, dim3(32, 16), dim3(256), 0, stream, Yb, Wpb, bp, (float*)d_out);
}